// Round 6
// baseline (561.583 us; speedup 1.0000x reference)
//
#include <hip/hip_runtime.h>

#define SEQ   512
#define BATCH 64
#define HID   1024
#define NX    8
#define SG    64          // s-groups per batch in fused attention
#define SROWS (SEQ / SG)  // 8 rows per group

// ---------------------------------------------------------------------------
// WVT[h][n] = WV[n][h]  (one-time 32x32 tiled transpose)
// ---------------------------------------------------------------------------
__global__ __launch_bounds__(256) void transpose_k(
    const float* __restrict__ in, float* __restrict__ outT)
{
    __shared__ float tile[32][33];
    const int bx = blockIdx.x * 32, by = blockIdx.y * 32;
    const int tx = threadIdx.x & 31, ty = threadIdx.x >> 5;
    #pragma unroll
    for (int r = ty; r < 32; r += 8)
        tile[r][tx] = in[(size_t)(by + r) * HID + bx + tx];
    __syncthreads();
    #pragma unroll
    for (int r = ty; r < 32; r += 8)
        outT[(size_t)(bx + r) * HID + by + tx] = tile[tx][r];
}

// ---------------------------------------------------------------------------
// gemv_y: yp[b, jg, n] = sum_{j in jg} x[b,j] * WK[j,n]
// grid (nc=4, jg=8, b=64) = 2048 blocks. Staging computes x[b, j-slice] from
// previous step's op partials + bias (or q at t==1); nc==0 writes out row t-1.
// ---------------------------------------------------------------------------
__global__ __launch_bounds__(256) void gemv_y_kernel(
    const float* __restrict__ WK, const float* __restrict__ q,
    const float* __restrict__ op, const float* __restrict__ bV,
    float* __restrict__ out, int t, float* __restrict__ yp)
{
    __shared__ float xs[128];
    const int nc = blockIdx.x, jg = blockIdx.y, b = blockIdx.z;
    const int tid = threadIdx.x;

    if (tid < 128) {
        const int j = jg * 128 + tid;
        float v;
        if (t == 1) {
            v = q[(size_t)b * HID + j];
        } else {
            v = bV[j];
            const float* __restrict__ p = op + (size_t)(b * 8) * HID + j;
            #pragma unroll
            for (int g = 0; g < 8; g++) v += p[(size_t)g * HID];
        }
        xs[tid] = v;
        if (nc == 0) out[((size_t)(b * NX + t - 1)) * HID + j] = v;
    }
    __syncthreads();

    const int n = nc * 256 + tid;
    const float* __restrict__ wp = WK + (size_t)(jg * 128) * HID + n;
    float acc = 0.f;
    #pragma unroll 8
    for (int j = 0; j < 128; j++)
        acc += xs[j] * wp[(size_t)j * HID];
    yp[((size_t)(b * 8 + jg)) * HID + n] = acc;
}

// ---------------------------------------------------------------------------
// fused_attn (single hidden pass): per (sg, b) block:
//   stage hs[8][1024] = hidden rows (32 KB) and ys = sum_g yp[b,g,:]  in LDS
//   sc[r]  = ys . hs[r]                   (4 waves x 2 rows, from LDS)
//   local softmax: m, we[r] = exp(sc-m), l = sum
//   zp[b,sg,h] = sum_r we[r] * hs[r][h]   (from LDS)
// ---------------------------------------------------------------------------
__global__ __launch_bounds__(256) void fused_attn_kernel(
    const float* __restrict__ hidden, const float* __restrict__ yp,
    float* __restrict__ zp, float* __restrict__ ml)
{
    const int sg = blockIdx.x;   // 0..63
    const int b  = blockIdx.y;   // 0..63
    const int tid = threadIdx.x;
    const int w = tid >> 6, lane = tid & 63;

    __shared__ float hs[SROWS][HID];   // 32 KiB
    __shared__ float ys[HID];          // 4 KiB
    __shared__ float sc[SROWS];
    __shared__ float we[SROWS];

    // ys = reduce of 8 yp partials
    for (int i = tid; i < HID; i += 256) {
        const float* __restrict__ p = yp + (size_t)(b * 8) * HID + i;
        float s = 0.f;
        #pragma unroll
        for (int g = 0; g < 8; g++) s += p[(size_t)g * HID];
        ys[i] = s;
    }
    // stage hidden rows: 8 rows x 256 float4, thread -> (row, col4)
    #pragma unroll
    for (int idx = tid; idx < SROWS * (HID / 4); idx += 256) {
        const int r = idx >> 8, c = (idx & 255) * 4;
        *(float4*)&hs[r][c] =
            *(const float4*)&hidden[((size_t)(sg * SROWS + r) * BATCH + b) * HID + c];
    }
    __syncthreads();

    // scores from LDS: wave w handles rows w*2, w*2+1
    #pragma unroll
    for (int ri = 0; ri < 2; ri++) {
        const int r = w * 2 + ri;
        float sum = 0.f;
        #pragma unroll
        for (int i = 0; i < 4; i++) {
            float4 hv = *(const float4*)&hs[r][lane * 16 + i * 4];
            float4 yv = *(const float4*)&ys[lane * 16 + i * 4];
            sum += hv.x * yv.x + hv.y * yv.y + hv.z * yv.z + hv.w * yv.w;
        }
        #pragma unroll
        for (int off = 32; off; off >>= 1) sum += __shfl_xor(sum, off);
        if (lane == 0) sc[r] = sum;
    }
    __syncthreads();

    float m = sc[0];
    #pragma unroll
    for (int i = 1; i < SROWS; i++) m = fmaxf(m, sc[i]);
    if (tid < SROWS) we[tid] = expf(sc[tid] - m);
    __syncthreads();
    float l = 0.f;
    #pragma unroll
    for (int i = 0; i < SROWS; i++) l += we[i];

    // zsum from LDS: thread owns h = tid*4 .. +3
    float4 acc = {0.f, 0.f, 0.f, 0.f};
    #pragma unroll
    for (int r = 0; r < SROWS; r++) {
        const float wv = we[r];
        float4 hv = *(const float4*)&hs[r][tid * 4];
        acc.x += wv * hv.x; acc.y += wv * hv.y;
        acc.z += wv * hv.z; acc.w += wv * hv.w;
    }
    *(float4*)(zp + ((size_t)(b * SG + sg)) * HID + tid * 4) = acc;
    if (tid == 0) {
        ml[(b * SG + sg) * 2 + 0] = m;
        ml[(b * SG + sg) * 2 + 1] = l;
    }
}

// ---------------------------------------------------------------------------
// gemv_out: op[b, hg, n] = sum_{h in hg} z[b,h] * WVT[h,n]
// grid (nc=4, hg=8, b=64). Staging applies global softmax rescale over SG
// groups using an LDS es[] table:
//   M = max_g m_g ; es[g] = e^{m_g-M} ; L = sum_g l_g es[g]
//   z[h] = sum_g zp[b,g,h] es[g] / L
// ---------------------------------------------------------------------------
__global__ __launch_bounds__(256) void gemv_out_kernel(
    const float* __restrict__ WVT, const float* __restrict__ zp,
    const float* __restrict__ ml, float* __restrict__ op)
{
    __shared__ float zs[128];
    __shared__ float es[SG];
    const int nc = blockIdx.x, hg = blockIdx.y, b = blockIdx.z;
    const int tid = threadIdx.x;

    float M = -1e30f;
    #pragma unroll
    for (int g = 0; g < SG; g++) M = fmaxf(M, ml[(b * SG + g) * 2]);
    if (tid < SG) es[tid] = expf(ml[(b * SG + tid) * 2] - M);
    __syncthreads();
    float L = 0.f;
    #pragma unroll
    for (int g = 0; g < SG; g++) L += ml[(b * SG + g) * 2 + 1] * es[g];
    const float invL = 1.0f / L;

    if (tid < 128) {
        const int h = hg * 128 + tid;
        float s = 0.f;
        #pragma unroll 8
        for (int g = 0; g < SG; g++)
            s += zp[((size_t)(b * SG + g)) * HID + h] * es[g];
        zs[tid] = s * invL;
    }
    __syncthreads();

    const int n = nc * 256 + tid;
    const float* __restrict__ wp = WVT + (size_t)(hg * 128) * HID + n;
    float acc = 0.f;
    #pragma unroll 8
    for (int h = 0; h < 128; h++)
        acc += zs[h] * wp[(size_t)h * HID];
    op[((size_t)(b * 8 + hg)) * HID + n] = acc;
}

// final output row t=NX-1: out = sum_g op + bias
__global__ __launch_bounds__(256) void reduce8_bias_kernel(
    const float* __restrict__ part, const float* __restrict__ bias,
    float* __restrict__ out, int t)
{
    const int idx = blockIdx.x * 256 + threadIdx.x;
    const int b = idx >> 10, n = idx & (HID - 1);
    float s = bias[n];
    #pragma unroll
    for (int g = 0; g < 8; g++) s += part[((size_t)b * 8 + g) * HID + n];
    out[((size_t)b * NX + t) * HID + n] = s;
}

// ---------------------------------------------------------------------------
extern "C" void kernel_launch(void* const* d_in, const int* in_sizes, int n_in,
                              void* d_out, int out_size, void* d_ws, size_t ws_size,
                              hipStream_t stream)
{
    const float* hidden = (const float*)d_in[1];
    const float* q      = (const float*)d_in[2];
    const float* WK     = (const float*)d_in[3];
    const float* WV     = (const float*)d_in[5];
    const float* bV     = (const float*)d_in[6];
    float* out = (float*)d_out;

    char* ws = (char*)d_ws;
    float* WVT = (float*)(ws);                    // 4 MiB
    float* yp  = (float*)(ws + (4  << 20));       // 2 MiB
    float* zp  = (float*)(ws + (6  << 20));       // 16 MiB
    float* ml  = (float*)(ws + (22 << 20));       // 32 KiB
    float* op  = (float*)(ws + (23 << 20));       // 2 MiB

    transpose_k<<<dim3(32, 32), 256, 0, stream>>>(WV, WVT);

    for (int t = 1; t < NX; t++) {
        gemv_y_kernel<<<dim3(4, 8, BATCH), 256, 0, stream>>>(
            WK, q, op, bV, out, t, yp);
        fused_attn_kernel<<<dim3(SG, BATCH), 256, 0, stream>>>(
            hidden, yp, zp, ml);
        gemv_out_kernel<<<dim3(4, 8, BATCH), 256, 0, stream>>>(
            WVT, zp, ml, op);
    }
    reduce8_bias_kernel<<<(BATCH * HID) / 256, 256, 0, stream>>>(
        op, bV, out, NX - 1);
}

// Round 7
// 405.502 us; speedup vs baseline: 1.3849x; 1.3849x over previous
//
#include <hip/hip_runtime.h>

#define SEQ   512
#define BATCH 64
#define HID   1024
#define NX    8
#define SG    64          // s-groups per batch in fused attention
#define SROWS (SEQ / SG)  // 8 rows per group

// ---------------------------------------------------------------------------
// WVT[h][n] = WV[n][h]  (one-time 32x32 tiled transpose)
// ---------------------------------------------------------------------------
__global__ __launch_bounds__(256) void transpose_k(
    const float* __restrict__ in, float* __restrict__ outT)
{
    __shared__ float tile[32][33];
    const int bx = blockIdx.x * 32, by = blockIdx.y * 32;
    const int tx = threadIdx.x & 31, ty = threadIdx.x >> 5;
    #pragma unroll
    for (int r = ty; r < 32; r += 8)
        tile[r][tx] = in[(size_t)(by + r) * HID + bx + tx];
    __syncthreads();
    #pragma unroll
    for (int r = ty; r < 32; r += 8)
        outT[(size_t)(bx + r) * HID + by + tx] = tile[tx][r];
}

// ---------------------------------------------------------------------------
// gemv_y: y[b, n] = sum_j x[b,j] * WK[j,n]    COMPLETE output (no partials).
// grid (nc=32, b=64) = 2048 blocks. Block = 32 n x 8 j-groups.
// x[b,:] = opfull[b,:] + bV (or q at t==1), staged in LDS; nc==0 writes
// the finished x as out row t-1.
// ---------------------------------------------------------------------------
__global__ __launch_bounds__(256) void gemv_y_kernel(
    const float* __restrict__ WK, const float* __restrict__ q,
    const float* __restrict__ opfull, const float* __restrict__ bV,
    float* __restrict__ out, int t, float* __restrict__ y)
{
    __shared__ float xs[HID];        // 4 KiB
    __shared__ float red[8 * 32];    // 1 KiB
    const int nc = blockIdx.x, b = blockIdx.y;
    const int tid = threadIdx.x;

    {
        const int j4 = tid * 4;
        float4 v;
        if (t == 1) {
            v = *(const float4*)(q + (size_t)b * HID + j4);
        } else {
            float4 o = *(const float4*)(opfull + (size_t)b * HID + j4);
            float4 bb = *(const float4*)(bV + j4);
            v.x = o.x + bb.x; v.y = o.y + bb.y;
            v.z = o.z + bb.z; v.w = o.w + bb.w;
        }
        *(float4*)(xs + j4) = v;
        if (nc == 0)
            *(float4*)(out + ((size_t)(b * NX + t - 1)) * HID + j4) = v;
    }
    __syncthreads();

    const int nl = tid & 31;          // 0..31
    const int jg = tid >> 5;          // 0..7
    const int n  = nc * 32 + nl;
    const float* __restrict__ wp = WK + (size_t)(jg * 128) * HID + n;
    const float* __restrict__ xr = xs + jg * 128;
    float acc = 0.f;
    #pragma unroll 8
    for (int jj = 0; jj < 128; jj++)
        acc += xr[jj] * wp[(size_t)jj * HID];
    red[jg * 32 + nl] = acc;
    __syncthreads();
    if (tid < 32) {
        float s = 0.f;
        #pragma unroll
        for (int g = 0; g < 8; g++) s += red[g * 32 + tid];
        y[(size_t)b * HID + nc * 32 + tid] = s;
    }
}

// ---------------------------------------------------------------------------
// fused_attn (register flash, single hidden pass): per (sg, b) block:
//   thread owns h-slice [tid*4, tid*4+4) of y and of 8 hidden rows (VGPRs)
//   sc[r] via per-thread dot + wave shuffle + LDS cross-wave reduce
//   local softmax (m, l); zp[b,sg,:] = sum_r we[r]*row_r from REGISTERS
// ---------------------------------------------------------------------------
__global__ __launch_bounds__(256) void fused_attn_kernel(
    const float* __restrict__ hidden, const float* __restrict__ y,
    float* __restrict__ zp, float* __restrict__ ml)
{
    const int sg = blockIdx.x;   // 0..63
    const int b  = blockIdx.y;   // 0..63
    const int tid = threadIdx.x;
    const int w = tid >> 6, lane = tid & 63;

    __shared__ float part[4 * SROWS];   // [wave][row]

    const int h4 = tid * 4;
    const float4 yv = *(const float4*)(y + (size_t)b * HID + h4);

    float4 hv[SROWS];
    float p[SROWS];
    #pragma unroll
    for (int r = 0; r < SROWS; r++) {
        hv[r] = *(const float4*)(
            hidden + ((size_t)(sg * SROWS + r) * BATCH + b) * HID + h4);
        p[r] = hv[r].x * yv.x + hv[r].y * yv.y + hv[r].z * yv.z + hv[r].w * yv.w;
    }
    #pragma unroll
    for (int r = 0; r < SROWS; r++) {
        float s = p[r];
        #pragma unroll
        for (int off = 32; off; off >>= 1) s += __shfl_xor(s, off);
        if (lane == 0) part[w * SROWS + r] = s;
    }
    __syncthreads();

    float sc[SROWS], m = -1e30f;
    #pragma unroll
    for (int r = 0; r < SROWS; r++) {
        sc[r] = part[0 * SROWS + r] + part[1 * SROWS + r]
              + part[2 * SROWS + r] + part[3 * SROWS + r];
        m = fmaxf(m, sc[r]);
    }
    float we[SROWS], l = 0.f;
    #pragma unroll
    for (int r = 0; r < SROWS; r++) { we[r] = expf(sc[r] - m); l += we[r]; }

    float4 acc = {0.f, 0.f, 0.f, 0.f};
    #pragma unroll
    for (int r = 0; r < SROWS; r++) {
        acc.x += we[r] * hv[r].x; acc.y += we[r] * hv[r].y;
        acc.z += we[r] * hv[r].z; acc.w += we[r] * hv[r].w;
    }
    *(float4*)(zp + ((size_t)(b * SG + sg)) * HID + h4) = acc;
    if (tid == 0) {
        ml[(b * SG + sg) * 2 + 0] = m;
        ml[(b * SG + sg) * 2 + 1] = l;
    }
}

// ---------------------------------------------------------------------------
// z_finalize: z[b,h] = (sum_g zp[b,g,h] * e^{m_g - M}) / L   (global softmax)
// grid (hc=16, b=64) = 1024 blocks. Block = 64 h x 4 g-quarters.
// zp read exactly once (16 MB), z = 256 KB out.
// ---------------------------------------------------------------------------
__global__ __launch_bounds__(256) void z_finalize_kernel(
    const float* __restrict__ zp, const float* __restrict__ ml,
    float* __restrict__ z)
{
    __shared__ float mls[2 * SG];    // interleaved (m,l)
    __shared__ float es[SG];
    __shared__ float red[4 * 64];
    const int hc = blockIdx.x, b = blockIdx.y;
    const int tid = threadIdx.x;

    if (tid < 2 * SG) mls[tid] = ml[b * 2 * SG + tid];
    __syncthreads();
    float M = -1e30f;
    #pragma unroll
    for (int g = 0; g < SG; g++) M = fmaxf(M, mls[2 * g]);
    if (tid < SG) es[tid] = expf(mls[2 * tid] - M);
    __syncthreads();
    float L = 0.f;
    #pragma unroll
    for (int g = 0; g < SG; g++) L += mls[2 * g + 1] * es[g];
    const float invL = 1.0f / L;

    const int hl = tid & 63;          // 0..63
    const int gq = tid >> 6;          // 0..3
    const int h  = hc * 64 + hl;
    const float* __restrict__ zpp = zp + ((size_t)(b * SG + gq * 16)) * HID + h;
    float acc = 0.f;
    #pragma unroll 4
    for (int g = 0; g < 16; g++)
        acc += zpp[(size_t)g * HID] * es[gq * 16 + g];
    red[gq * 64 + hl] = acc;
    __syncthreads();
    if (tid < 64) {
        float s = red[tid] + red[64 + tid] + red[128 + tid] + red[192 + tid];
        z[(size_t)b * HID + hc * 64 + tid] = s * invL;
    }
}

// ---------------------------------------------------------------------------
// gemv_out: opfull[b, n] = sum_h z[b,h] * WVT[h,n]   COMPLETE output.
// grid (nc=32, b=64), block = 32 n x 8 h-groups.  (bias NOT added here;
// next step's gemv_y staging adds bV, final row handled by final_out.)
// ---------------------------------------------------------------------------
__global__ __launch_bounds__(256) void gemv_out_kernel(
    const float* __restrict__ WVT, const float* __restrict__ z,
    float* __restrict__ opfull)
{
    __shared__ float zs[HID];
    __shared__ float red[8 * 32];
    const int nc = blockIdx.x, b = blockIdx.y;
    const int tid = threadIdx.x;

    *(float4*)(zs + tid * 4) = *(const float4*)(z + (size_t)b * HID + tid * 4);
    __syncthreads();

    const int nl = tid & 31;
    const int hg = tid >> 5;
    const int n  = nc * 32 + nl;
    const float* __restrict__ wp = WVT + (size_t)(hg * 128) * HID + n;
    const float* __restrict__ zr = zs + hg * 128;
    float acc = 0.f;
    #pragma unroll 8
    for (int hh = 0; hh < 128; hh++)
        acc += zr[hh] * wp[(size_t)hh * HID];
    red[hg * 32 + nl] = acc;
    __syncthreads();
    if (tid < 32) {
        float s = 0.f;
        #pragma unroll
        for (int g = 0; g < 8; g++) s += red[g * 32 + tid];
        opfull[(size_t)b * HID + nc * 32 + tid] = s;
    }
}

// final output row t=NX-1: out = opfull + bias
__global__ __launch_bounds__(256) void final_out_kernel(
    const float* __restrict__ opfull, const float* __restrict__ bias,
    float* __restrict__ out)
{
    const int idx = blockIdx.x * 256 + threadIdx.x;
    const int b = idx >> 10, n = idx & (HID - 1);
    out[((size_t)b * NX + NX - 1) * HID + n] = opfull[idx] + bias[n];
}

// ---------------------------------------------------------------------------
extern "C" void kernel_launch(void* const* d_in, const int* in_sizes, int n_in,
                              void* d_out, int out_size, void* d_ws, size_t ws_size,
                              hipStream_t stream)
{
    const float* hidden = (const float*)d_in[1];
    const float* q      = (const float*)d_in[2];
    const float* WK     = (const float*)d_in[3];
    const float* WV     = (const float*)d_in[5];
    const float* bV     = (const float*)d_in[6];
    float* out = (float*)d_out;

    char* ws = (char*)d_ws;
    float* WVT    = (float*)(ws);                  // 4 MiB
    float* y      = (float*)(ws + (4  << 20));     // 256 KiB
    float* z      = (float*)(ws + (4  << 20) + (256 << 10));   // 256 KiB
    float* opfull = (float*)(ws + (5  << 20));     // 256 KiB
    float* ml     = (float*)(ws + (5  << 20) + (256 << 10));   // 32 KiB
    float* zp     = (float*)(ws + (6  << 20));     // 16 MiB

    transpose_k<<<dim3(32, 32), 256, 0, stream>>>(WV, WVT);

    for (int t = 1; t < NX; t++) {
        gemv_y_kernel<<<dim3(32, BATCH), 256, 0, stream>>>(
            WK, q, opfull, bV, out, t, y);
        fused_attn_kernel<<<dim3(SG, BATCH), 256, 0, stream>>>(
            hidden, y, zp, ml);
        z_finalize_kernel<<<dim3(16, BATCH), 256, 0, stream>>>(zp, ml, z);
        gemv_out_kernel<<<dim3(32, BATCH), 256, 0, stream>>>(WVT, z, opfull);
    }
    final_out_kernel<<<(BATCH * HID) / 256, 256, 0, stream>>>(opfull, bV, out);
}